// Round 2
// baseline (446.004 us; speedup 1.0000x reference)
//
#include <hip/hip_runtime.h>

#define BN 128
#define DTCF 512
#define TT 1024
#define GAF 256
#define DKK 32
#define HID 64
#define NCLS 4
#define LNEPS 1e-5f

// ---------------------------------------------------------------------------
// Kernel 1: per-batch tiny precompute.
//   KV[b,k]  = sum_g gaf[b,g] * Wkv[k,g]
//   u[b,d]   = sum_k KV[b,k] * Wout[d,k]      (= (Wout @ KV)[d])
//   qv[b,d]  = sum_k KV[b,k] * Wq[k,d]        (= (Wq^T @ KV)[d])
//   muu[b]   = mean_d u ; varu[b] = mean_d u^2 - muu^2
// ---------------------------------------------------------------------------
__global__ __launch_bounds__(256) void k_prep(
    const float* __restrict__ gaf, const float* __restrict__ Wq,
    const float* __restrict__ Wkv, const float* __restrict__ Wout,
    float* __restrict__ u, float* __restrict__ qv,
    float* __restrict__ muu, float* __restrict__ varu)
{
    int b = blockIdx.x, tid = threadIdx.x;
    __shared__ float gaf_s[GAF];
    __shared__ float kv_s[DKK];
    __shared__ float red[16];

    gaf_s[tid & (GAF - 1)] = gaf[b * GAF + (tid & (GAF - 1))];
    __syncthreads();

    if (tid < DKK) {
        float acc = 0.f;
        for (int g = 0; g < GAF; ++g) acc += gaf_s[g] * Wkv[tid * GAF + g];
        kv_s[tid] = acc;
    }
    __syncthreads();

    float su = 0.f, suu = 0.f;
    for (int d = tid; d < DTCF; d += 256) {
        float uu = 0.f, qq = 0.f;
        #pragma unroll
        for (int k = 0; k < DKK; ++k) {
            float kv = kv_s[k];
            uu += kv * Wout[d * DKK + k];
            qq += kv * Wq[k * DTCF + d];
        }
        u[b * DTCF + d] = uu;
        qv[b * DTCF + d] = qq;
        su += uu; suu += uu * uu;
    }
    int lane = tid & 63, wv = tid >> 6;
    for (int off = 32; off > 0; off >>= 1) {
        su  += __shfl_down(su, off);
        suu += __shfl_down(suu, off);
    }
    if (lane == 0) { red[wv] = su; red[8 + wv] = suu; }
    __syncthreads();
    if (tid == 0) {
        float s  = red[0] + red[1] + red[2] + red[3];
        float ss = red[8] + red[9] + red[10] + red[11];
        float m = s * (1.f / DTCF);
        muu[b]  = m;
        varu[b] = ss * (1.f / DTCF) - m * m;
    }
}

// ---------------------------------------------------------------------------
// Kernel 2: pass A over tcf (256 MB fp32). Per (b,t): reductions over d.
//   sx, sxx, sxu (x dot u[b,:]), sxq (x dot qv[b,:])
// Thread owns one t; consecutive lanes read consecutive t -> coalesced.
// ---------------------------------------------------------------------------
__global__ __launch_bounds__(256) void k_passA(
    const float* __restrict__ tcf, const float* __restrict__ u,
    const float* __restrict__ qv, const float* __restrict__ muu,
    float* __restrict__ mx_o, float* __restrict__ varx_o,
    float* __restrict__ cov_o, float* __restrict__ score_o)
{
    int b = blockIdx.x, tc = blockIdx.y, tid = threadIdx.x;
    int t = tc * 256 + tid;
    __shared__ float u_s[DTCF], qv_s[DTCF];
    for (int i = tid; i < DTCF; i += 256) {
        u_s[i]  = u[b * DTCF + i];
        qv_s[i] = qv[b * DTCF + i];
    }
    __syncthreads();

    const float* base = tcf + (size_t)b * DTCF * TT + t;
    float sx = 0.f, sxx = 0.f, sxu = 0.f, sxq = 0.f;
    #pragma unroll 8
    for (int d = 0; d < DTCF; ++d) {
        float v = base[(size_t)d * TT];
        sx  += v;
        sxx += v * v;
        sxu += v * u_s[d];
        sxq += v * qv_s[d];
    }
    float mx = sx * (1.f / DTCF);
    size_t o = (size_t)b * TT + t;
    mx_o[o]    = mx;
    varx_o[o]  = sxx * (1.f / DTCF) - mx * mx;
    cov_o[o]   = sxu * (1.f / DTCF) - mx * muu[b];
    score_o[o] = sxq * 0.17677669529663687f;  // 1/sqrt(32)
}

// ---------------------------------------------------------------------------
// Kernel 3: per-b softmax over T + LN1 rstd + scalars S2, S3.
//   w_t = softmax(score)_t ; var_t = varx + 2w*cov + w^2*varu
//   r_t = rsqrt(var+eps) ; S2 = mean_t r*w ; S3 = mean_t r*mx
// ---------------------------------------------------------------------------
__global__ __launch_bounds__(256) void k_soft(
    const float* __restrict__ score, const float* __restrict__ varx,
    const float* __restrict__ cov, const float* __restrict__ mx,
    const float* __restrict__ varu,
    float* __restrict__ r_o, float* __restrict__ S2, float* __restrict__ S3)
{
    int b = blockIdx.x, tid = threadIdx.x;
    int lane = tid & 63, wv = tid >> 6;
    __shared__ float red[16];
    const float* sc = score + (size_t)b * TT;

    float s0 = sc[tid], s1 = sc[tid + 256], s2v = sc[tid + 512], s3v = sc[tid + 768];
    float m = fmaxf(fmaxf(s0, s1), fmaxf(s2v, s3v));
    for (int off = 32; off > 0; off >>= 1) m = fmaxf(m, __shfl_xor(m, off));
    if (lane == 0) red[wv] = m;
    __syncthreads();
    m = fmaxf(fmaxf(red[0], red[1]), fmaxf(red[2], red[3]));

    float e0 = __expf(s0 - m), e1 = __expf(s1 - m);
    float e2 = __expf(s2v - m), e3 = __expf(s3v - m);
    float sum = e0 + e1 + e2 + e3;
    for (int off = 32; off > 0; off >>= 1) sum += __shfl_xor(sum, off);
    __syncthreads();
    if (lane == 0) red[4 + wv] = sum;
    __syncthreads();
    sum = red[4] + red[5] + red[6] + red[7];
    float inv = 1.f / sum;
    float vu = varu[b];

    float e[4] = {e0, e1, e2, e3};
    float s2a = 0.f, s3a = 0.f;
    #pragma unroll
    for (int i = 0; i < 4; ++i) {
        size_t o = (size_t)b * TT + tid + i * 256;
        float w = e[i] * inv;
        float vr = varx[o] + 2.f * w * cov[o] + w * w * vu;
        float rr = rsqrtf(vr + LNEPS);
        r_o[o] = rr;
        s2a += rr * w;
        s3a += rr * mx[o];
    }
    for (int off = 32; off > 0; off >>= 1) {
        s2a += __shfl_xor(s2a, off);
        s3a += __shfl_xor(s3a, off);
    }
    __syncthreads();
    if (lane == 0) { red[wv] = s2a; red[8 + wv] = s3a; }
    __syncthreads();
    if (tid == 0) {
        S2[b] = (red[0] + red[1] + red[2] + red[3]) * (1.f / TT);
        S3[b] = (red[8] + red[9] + red[10] + red[11]) * (1.f / TT);
    }
}

// ---------------------------------------------------------------------------
// Kernel 4: pass B over tcf. Per (b,d): dot(r[b,:], tcf[b,d,:]) along the
// contiguous t axis; one wave per d-row, lane holds 16 floats (4x float4).
// Emits pooled (post-LN1-affine, pre-MLP).
// ---------------------------------------------------------------------------
__global__ __launch_bounds__(256) void k_passB(
    const float* __restrict__ tcf, const float* __restrict__ r,
    const float* __restrict__ u, const float* __restrict__ muu,
    const float* __restrict__ S2, const float* __restrict__ S3,
    const float* __restrict__ g1, const float* __restrict__ be1,
    float* __restrict__ pooled)
{
    int b = blockIdx.x, dblk = blockIdx.y;
    int tid = threadIdx.x, wv = tid >> 6, lane = tid & 63;
    int d = dblk * 4 + wv;

    const float* row = tcf + ((size_t)b * DTCF + d) * TT + lane * 16;
    const float* rb  = r + (size_t)b * TT + lane * 16;

    float4 x0 = *(const float4*)(row);
    float4 x1 = *(const float4*)(row + 4);
    float4 x2 = *(const float4*)(row + 8);
    float4 x3 = *(const float4*)(row + 12);
    float4 r0 = *(const float4*)(rb);
    float4 r1 = *(const float4*)(rb + 4);
    float4 r2 = *(const float4*)(rb + 8);
    float4 r3 = *(const float4*)(rb + 12);

    float acc = 0.f;
    acc += r0.x * x0.x + r0.y * x0.y + r0.z * x0.z + r0.w * x0.w;
    acc += r1.x * x1.x + r1.y * x1.y + r1.z * x1.z + r1.w * x1.w;
    acc += r2.x * x2.x + r2.y * x2.y + r2.z * x2.z + r2.w * x2.w;
    acc += r3.x * x3.x + r3.y * x3.y + r3.z * x3.z + r3.w * x3.w;

    for (int off = 32; off > 0; off >>= 1) acc += __shfl_down(acc, off);

    if (lane == 0) {
        float pd = acc * (1.f / TT) - S3[b] + (u[b * DTCF + d] - muu[b]) * S2[b];
        pooled[b * DTCF + d] = g1[d] * pd + be1[d];
    }
}

// ---------------------------------------------------------------------------
// Kernel 5: per-b head. h = elu(LN(pooled @ W1^T + b1)); out = h @ W2^T + b2.
// One wave per b; lane j owns hidden unit j (HID == 64 == wave size).
// ---------------------------------------------------------------------------
__global__ __launch_bounds__(64) void k_head(
    const float* __restrict__ pooled, const float* __restrict__ W1,
    const float* __restrict__ b1, const float* __restrict__ g2,
    const float* __restrict__ be2, const float* __restrict__ W2,
    const float* __restrict__ b2o, float* __restrict__ out)
{
    int b = blockIdx.x, j = threadIdx.x;
    __shared__ float p_s[DTCF];
    for (int i = j; i < DTCF; i += 64) p_s[i] = pooled[b * DTCF + i];
    __syncthreads();

    float h = 0.f;
    for (int dd = 0; dd < DTCF; ++dd) h += p_s[dd] * W1[j * DTCF + dd];
    h += b1[j];

    float mu = h;
    for (int off = 32; off > 0; off >>= 1) mu += __shfl_xor(mu, off);
    mu *= (1.f / HID);
    float df = h - mu;
    float vr = df * df;
    for (int off = 32; off > 0; off >>= 1) vr += __shfl_xor(vr, off);
    vr *= (1.f / HID);
    float hn = df * rsqrtf(vr + LNEPS) * g2[j] + be2[j];
    float he = hn > 0.f ? hn : expm1f(hn);

    #pragma unroll
    for (int c = 0; c < NCLS; ++c) {
        float v = he * W2[c * HID + j];
        for (int off = 32; off > 0; off >>= 1) v += __shfl_xor(v, off);
        if (j == 0) out[b * NCLS + c] = v + b2o[c];
    }
}

extern "C" void kernel_launch(void* const* d_in, const int* in_sizes, int n_in,
                              void* d_out, int out_size, void* d_ws, size_t ws_size,
                              hipStream_t stream)
{
    const float* tcf  = (const float*)d_in[0];
    const float* gaf  = (const float*)d_in[1];
    const float* Wq   = (const float*)d_in[2];
    const float* Wkv  = (const float*)d_in[3];
    const float* Wout = (const float*)d_in[4];
    const float* ln1g = (const float*)d_in[5];
    const float* ln1b = (const float*)d_in[6];
    const float* W1   = (const float*)d_in[7];
    const float* b1   = (const float*)d_in[8];
    const float* ln2g = (const float*)d_in[9];
    const float* ln2b = (const float*)d_in[10];
    const float* W2   = (const float*)d_in[11];
    const float* b2   = (const float*)d_in[12];

    float* ws     = (float*)d_ws;
    float* u      = ws;                  // B*DTCF
    float* qv     = u + BN * DTCF;       // B*DTCF
    float* muu    = qv + BN * DTCF;      // B
    float* varu   = muu + BN;            // B
    float* mx     = varu + BN;           // B*T
    float* varx   = mx + BN * TT;        // B*T
    float* cov    = varx + BN * TT;      // B*T
    float* score  = cov + BN * TT;       // B*T
    float* r      = score + BN * TT;     // B*T
    float* S2     = r + BN * TT;         // B
    float* S3     = S2 + BN;             // B
    float* pooled = S3 + BN;             // B*DTCF

    k_prep<<<BN, 256, 0, stream>>>(gaf, Wq, Wkv, Wout, u, qv, muu, varu);
    k_passA<<<dim3(BN, TT / 256), 256, 0, stream>>>(tcf, u, qv, muu, mx, varx, cov, score);
    k_soft<<<BN, 256, 0, stream>>>(score, varx, cov, mx, varu, r, S2, S3);
    k_passB<<<dim3(BN, DTCF / 4), 256, 0, stream>>>(tcf, r, u, muu, S2, S3, ln1g, ln1b, pooled);
    k_head<<<BN, 64, 0, stream>>>(pooled, W1, b1, ln2g, ln2b, W2, b2, (float*)d_out);
}

// Round 3
// 444.253 us; speedup vs baseline: 1.0039x; 1.0039x over previous
//
#include <hip/hip_runtime.h>

#define BN 128
#define DTCF 512
#define TT 1024
#define GAF 256
#define DKK 32
#define HID 64
#define NCLS 4
#define LNEPS 1e-5f
#define DC 8          // d-chunks in pass A
#define DCL (DTCF/DC) // 64 d per chunk

// ---------------------------------------------------------------------------
// Kernel 1: per-batch tiny precompute (+ W1 transpose in tail blocks).
//   KV[b,k]  = sum_g gaf[b,g] * Wkv[k,g]
//   u[b,d]   = sum_k KV[b,k] * Wout[d,k]
//   qv[b,d]  = sum_k KV[b,k] * Wq[k,d]
//   muu[b], varu[b] over d.  Blocks [BN, BN+8): W1t[dd*64+j] = W1[j*512+dd].
// ---------------------------------------------------------------------------
__global__ __launch_bounds__(256) void k_prep(
    const float* __restrict__ gaf, const float* __restrict__ Wq,
    const float* __restrict__ Wkv, const float* __restrict__ Wout,
    const float* __restrict__ W1,
    float* __restrict__ u, float* __restrict__ qv,
    float* __restrict__ muu, float* __restrict__ varu,
    float* __restrict__ W1t)
{
    int b = blockIdx.x, tid = threadIdx.x;

    if (b >= BN) {                       // W1 transpose: 8 blocks x 4096 elems
        int e0 = (b - BN) * 4096 + tid * 16;
        int j  = e0 >> 9;                // 16 elems stay within one source row
        int dd = e0 & 511;
        #pragma unroll
        for (int i = 0; i < 16; ++i)
            W1t[(dd + i) * HID + j] = W1[j * DTCF + dd + i];
        return;
    }

    __shared__ float gaf_s[GAF];
    __shared__ float kvp[DKK][9];
    __shared__ float kv_s[DKK];
    __shared__ float red[16];

    gaf_s[tid & (GAF - 1)] = gaf[b * GAF + (tid & (GAF - 1))];
    __syncthreads();

    {   // KV: 8 threads per k
        int k = tid >> 3, p8 = tid & 7;
        float acc = 0.f;
        #pragma unroll
        for (int g = p8 * 32; g < p8 * 32 + 32; ++g)
            acc += gaf_s[g] * Wkv[k * GAF + g];
        kvp[k][p8] = acc;
    }
    __syncthreads();
    if (tid < DKK) {
        float a = 0.f;
        #pragma unroll
        for (int p = 0; p < 8; ++p) a += kvp[tid][p];
        kv_s[tid] = a;
    }
    __syncthreads();

    float su = 0.f, suu = 0.f;
    for (int d = tid; d < DTCF; d += 256) {
        float uu = 0.f, qq = 0.f;
        #pragma unroll
        for (int k = 0; k < DKK; ++k) {
            float kv = kv_s[k];
            uu += kv * Wout[d * DKK + k];
            qq += kv * Wq[k * DTCF + d];
        }
        u[b * DTCF + d] = uu;
        qv[b * DTCF + d] = qq;
        su += uu; suu += uu * uu;
    }
    int lane = tid & 63, wv = tid >> 6;
    for (int off = 32; off > 0; off >>= 1) {
        su  += __shfl_down(su, off);
        suu += __shfl_down(suu, off);
    }
    if (lane == 0) { red[wv] = su; red[8 + wv] = suu; }
    __syncthreads();
    if (tid == 0) {
        float s  = red[0] + red[1] + red[2] + red[3];
        float ss = red[8] + red[9] + red[10] + red[11];
        float m = s * (1.f / DTCF);
        muu[b]  = m;
        varu[b] = ss * (1.f / DTCF) - m * m;
    }
}

// ---------------------------------------------------------------------------
// Kernel 2: pass A, d-split. Grid (BN, DC); block covers all T, thread owns
// 4 consecutive t (float4 loads, 1KB per wave-instr). 64 d per chunk.
// Emits 4 partial sums per (b,chunk,t) to ws.
// ---------------------------------------------------------------------------
__global__ __launch_bounds__(256) void k_passA(
    const float* __restrict__ tcf, const float* __restrict__ u,
    const float* __restrict__ qv, float* __restrict__ part)
{
    int b = blockIdx.x, dc = blockIdx.y, tid = threadIdx.x;
    __shared__ float u_s[DCL], qv_s[DCL];
    if (tid < DCL) u_s[tid] = u[b * DTCF + dc * DCL + tid];
    else if (tid < 2 * DCL) qv_s[tid - DCL] = qv[b * DTCF + dc * DCL + (tid - DCL)];
    __syncthreads();

    int t0 = tid * 4;
    const float* base = tcf + ((size_t)b * DTCF + dc * DCL) * TT + t0;
    float4 sx = {0,0,0,0}, sxx = {0,0,0,0}, sxu = {0,0,0,0}, sxq = {0,0,0,0};
    #pragma unroll 4
    for (int d = 0; d < DCL; ++d) {
        float4 v = *(const float4*)(base + (size_t)d * TT);
        float uu = u_s[d], qq = qv_s[d];
        sx.x += v.x; sx.y += v.y; sx.z += v.z; sx.w += v.w;
        sxx.x += v.x*v.x; sxx.y += v.y*v.y; sxx.z += v.z*v.z; sxx.w += v.w*v.w;
        sxu.x += v.x*uu; sxu.y += v.y*uu; sxu.z += v.z*uu; sxu.w += v.w*uu;
        sxq.x += v.x*qq; sxq.y += v.y*qq; sxq.z += v.z*qq; sxq.w += v.w*qq;
    }
    float* p = part + (((size_t)b * DC + dc) * 4) * TT + t0;
    *(float4*)(p)          = sx;
    *(float4*)(p + TT)     = sxx;
    *(float4*)(p + 2 * TT) = sxu;
    *(float4*)(p + 3 * TT) = sxq;
}

// ---------------------------------------------------------------------------
// Kernel 3: combine partials + softmax over T + r_t + S2,S3 per b.
// ---------------------------------------------------------------------------
__global__ __launch_bounds__(256) void k_soft(
    const float* __restrict__ part, const float* __restrict__ muu,
    const float* __restrict__ varu,
    float* __restrict__ r_o, float* __restrict__ S2, float* __restrict__ S3)
{
    int b = blockIdx.x, tid = threadIdx.x;
    int lane = tid & 63, wv = tid >> 6;
    __shared__ float red[16];
    int t0 = tid * 4;

    float4 sx = {0,0,0,0}, sxx = {0,0,0,0}, sxu = {0,0,0,0}, sxq = {0,0,0,0};
    #pragma unroll
    for (int dc = 0; dc < DC; ++dc) {
        const float* p = part + (((size_t)b * DC + dc) * 4) * TT + t0;
        float4 a = *(const float4*)(p);
        float4 bq = *(const float4*)(p + TT);
        float4 c = *(const float4*)(p + 2 * TT);
        float4 dq = *(const float4*)(p + 3 * TT);
        sx.x += a.x; sx.y += a.y; sx.z += a.z; sx.w += a.w;
        sxx.x += bq.x; sxx.y += bq.y; sxx.z += bq.z; sxx.w += bq.w;
        sxu.x += c.x; sxu.y += c.y; sxu.z += c.z; sxu.w += c.w;
        sxq.x += dq.x; sxq.y += dq.y; sxq.z += dq.z; sxq.w += dq.w;
    }
    float mu = muu[b], vu = varu[b];
    const float inv_d = 1.f / DTCF, scale = 0.17677669529663687f;
    float mx[4], vx[4], cv[4], sc[4];
    float sxa[4] = {sx.x, sx.y, sx.z, sx.w};
    float sxxa[4] = {sxx.x, sxx.y, sxx.z, sxx.w};
    float sxua[4] = {sxu.x, sxu.y, sxu.z, sxu.w};
    float sxqa[4] = {sxq.x, sxq.y, sxq.z, sxq.w};
    #pragma unroll
    for (int i = 0; i < 4; ++i) {
        mx[i] = sxa[i] * inv_d;
        vx[i] = sxxa[i] * inv_d - mx[i] * mx[i];
        cv[i] = sxua[i] * inv_d - mx[i] * mu;
        sc[i] = sxqa[i] * scale;
    }

    float m = fmaxf(fmaxf(sc[0], sc[1]), fmaxf(sc[2], sc[3]));
    for (int off = 32; off > 0; off >>= 1) m = fmaxf(m, __shfl_xor(m, off));
    if (lane == 0) red[wv] = m;
    __syncthreads();
    m = fmaxf(fmaxf(red[0], red[1]), fmaxf(red[2], red[3]));

    float e[4], sum = 0.f;
    #pragma unroll
    for (int i = 0; i < 4; ++i) { e[i] = __expf(sc[i] - m); sum += e[i]; }
    for (int off = 32; off > 0; off >>= 1) sum += __shfl_xor(sum, off);
    if (lane == 0) red[4 + wv] = sum;
    __syncthreads();
    sum = red[4] + red[5] + red[6] + red[7];
    float inv = 1.f / sum;

    float rr4[4], s2a = 0.f, s3a = 0.f;
    #pragma unroll
    for (int i = 0; i < 4; ++i) {
        float w = e[i] * inv;
        float vr = vx[i] + 2.f * w * cv[i] + w * w * vu;
        float rr = rsqrtf(vr + LNEPS);
        rr4[i] = rr;
        s2a += rr * w;
        s3a += rr * mx[i];
    }
    *(float4*)(r_o + (size_t)b * TT + t0) = make_float4(rr4[0], rr4[1], rr4[2], rr4[3]);

    for (int off = 32; off > 0; off >>= 1) {
        s2a += __shfl_xor(s2a, off);
        s3a += __shfl_xor(s3a, off);
    }
    if (lane == 0) { red[8 + wv] = s2a; red[12 + wv] = s3a; }
    __syncthreads();
    if (tid == 0) {
        S2[b] = (red[8] + red[9] + red[10] + red[11]) * (1.f / TT);
        S3[b] = (red[12] + red[13] + red[14] + red[15]) * (1.f / TT);
    }
}

// ---------------------------------------------------------------------------
// Kernel 4: pass B. One wave per (b,d) row: dot(r[b,:], tcf[b,d,:]),
// dense 1KB per wave-instr (lane*4 + i*256). Emits pooled (post-LN1 affine).
// ---------------------------------------------------------------------------
__global__ __launch_bounds__(256) void k_passB(
    const float* __restrict__ tcf, const float* __restrict__ r,
    const float* __restrict__ u, const float* __restrict__ muu,
    const float* __restrict__ S2, const float* __restrict__ S3,
    const float* __restrict__ g1, const float* __restrict__ be1,
    float* __restrict__ pooled)
{
    int b = blockIdx.x, dblk = blockIdx.y;
    int tid = threadIdx.x, wv = tid >> 6, lane = tid & 63;
    int d = dblk * 4 + wv;

    const float* row = tcf + ((size_t)b * DTCF + d) * TT;
    const float* rb  = r + (size_t)b * TT;

    float acc = 0.f;
    #pragma unroll
    for (int i = 0; i < 4; ++i) {
        float4 x = *(const float4*)(row + i * 256 + lane * 4);
        float4 rv = *(const float4*)(rb + i * 256 + lane * 4);
        acc += rv.x * x.x + rv.y * x.y + rv.z * x.z + rv.w * x.w;
    }
    for (int off = 32; off > 0; off >>= 1) acc += __shfl_down(acc, off);

    if (lane == 0) {
        float pd = acc * (1.f / TT) - S3[b] + (u[b * DTCF + d] - muu[b]) * S2[b];
        pooled[b * DTCF + d] = g1[d] * pd + be1[d];
    }
}

// ---------------------------------------------------------------------------
// Kernel 5: head. Block = 4 waves; wave wv covers dd-chunk of 128, lane j owns
// hidden unit j via coalesced W1t reads. Wave 0 finishes LN2+ELU+classes.
// ---------------------------------------------------------------------------
__global__ __launch_bounds__(256) void k_head(
    const float* __restrict__ pooled, const float* __restrict__ W1t,
    const float* __restrict__ b1, const float* __restrict__ g2,
    const float* __restrict__ be2, const float* __restrict__ W2,
    const float* __restrict__ b2o, float* __restrict__ out)
{
    int b = blockIdx.x, tid = threadIdx.x;
    int j = tid & 63, wv = tid >> 6;
    __shared__ float p_s[DTCF];
    __shared__ float hred[4][HID];
    for (int i = tid; i < DTCF; i += 256) p_s[i] = pooled[b * DTCF + i];
    __syncthreads();

    float hp = 0.f;
    #pragma unroll 8
    for (int i = 0; i < 128; ++i) {
        int dd = wv * 128 + i;
        hp += p_s[dd] * W1t[dd * HID + j];
    }
    hred[wv][j] = hp;
    __syncthreads();

    if (wv == 0) {
        float h = hred[0][j] + hred[1][j] + hred[2][j] + hred[3][j] + b1[j];
        float mu = h;
        for (int off = 32; off > 0; off >>= 1) mu += __shfl_xor(mu, off);
        mu *= (1.f / HID);
        float df = h - mu;
        float vr = df * df;
        for (int off = 32; off > 0; off >>= 1) vr += __shfl_xor(vr, off);
        vr *= (1.f / HID);
        float hn = df * rsqrtf(vr + LNEPS) * g2[j] + be2[j];
        float he = hn > 0.f ? hn : expm1f(hn);

        #pragma unroll
        for (int c = 0; c < NCLS; ++c) {
            float v = he * W2[c * HID + j];
            for (int off = 32; off > 0; off >>= 1) v += __shfl_xor(v, off);
            if (j == 0) out[b * NCLS + c] = v + b2o[c];
        }
    }
}

extern "C" void kernel_launch(void* const* d_in, const int* in_sizes, int n_in,
                              void* d_out, int out_size, void* d_ws, size_t ws_size,
                              hipStream_t stream)
{
    const float* tcf  = (const float*)d_in[0];
    const float* gaf  = (const float*)d_in[1];
    const float* Wq   = (const float*)d_in[2];
    const float* Wkv  = (const float*)d_in[3];
    const float* Wout = (const float*)d_in[4];
    const float* ln1g = (const float*)d_in[5];
    const float* ln1b = (const float*)d_in[6];
    const float* W1   = (const float*)d_in[7];
    const float* b1   = (const float*)d_in[8];
    const float* ln2g = (const float*)d_in[9];
    const float* ln2b = (const float*)d_in[10];
    const float* W2   = (const float*)d_in[11];
    const float* b2   = (const float*)d_in[12];

    float* ws     = (float*)d_ws;
    float* u      = ws;                   // B*DTCF
    float* qv     = u + BN * DTCF;        // B*DTCF
    float* muu    = qv + BN * DTCF;       // B
    float* varu   = muu + BN;             // B
    float* r      = varu + BN;            // B*T
    float* S2     = r + BN * TT;          // B
    float* S3     = S2 + BN;              // B
    float* pooled = S3 + BN;              // B*DTCF
    float* W1t    = pooled + BN * DTCF;   // 512*64
    float* part   = W1t + DTCF * HID;     // B*DC*4*T = 4M floats

    k_prep<<<BN + 8, 256, 0, stream>>>(gaf, Wq, Wkv, Wout, W1, u, qv, muu, varu, W1t);
    k_passA<<<dim3(BN, DC), 256, 0, stream>>>(tcf, u, qv, part);
    k_soft<<<BN, 256, 0, stream>>>(part, muu, varu, r, S2, S3);
    k_passB<<<dim3(BN, DTCF / 4), 256, 0, stream>>>(tcf, r, u, muu, S2, S3, ln1g, ln1b, pooled);
    k_head<<<BN, 256, 0, stream>>>(pooled, W1t, b1, ln2g, ln2b, W2, b2, (float*)d_out);
}